// Round 2
// baseline (7753.840 us; speedup 1.0000x reference)
//
#include <hip/hip_runtime.h>
#include <hip/hip_bf16.h>
#include <math.h>

#define B_   8
#define CL_  2048
#define TT_  1024
#define T_   3072      // CL + TT
#define D_   768
#define AD_  320
#define L_   6
#define H_   12
#define F_   3072
#define HD_  64
#define BH_  (B_*H_)
#define BT_  (B_*T_)   // 24576 rows

typedef __bf16 bf16x8 __attribute__((ext_vector_type(8)));
typedef float  f32x4  __attribute__((ext_vector_type(4)));

__device__ __forceinline__ float bf2f(ushort h){
  union { unsigned u; float f; } v; v.u = ((unsigned)h) << 16; return v.f;
}
__device__ __forceinline__ ushort f2bf(float f){
  union { float f; unsigned u; } v; v.f = f;
  unsigned u = v.u;
  return (ushort)((u + 0x7fffu + ((u >> 16) & 1u)) >> 16);  // RNE
}

// ---------------------------------------------------------------------------
// Zero a float4 range (replaces hipMemsetAsync: graph-capture-safe).
// ---------------------------------------------------------------------------
__global__ __launch_bounds__(256)
void zero_k(float4* __restrict__ p, int n4)
{
  int i = blockIdx.x*256 + threadIdx.x;
  if (i < n4) p[i] = (float4){0.f,0.f,0.f,0.f};
}

// ---------------------------------------------------------------------------
// Transpose + fp32->bf16 convert:  in (K,N) fp32 row-major -> out (N,K) bf16.
// grid: (N/64, K/64), block 256.
// ---------------------------------------------------------------------------
__global__ __launch_bounds__(256)
void tconv_k(const float* __restrict__ in, ushort* __restrict__ out, int K, int N)
{
  __shared__ ushort tile[64*65];
  int n0 = blockIdx.x*64, k0 = blockIdx.y*64;
  int c  = threadIdx.x & 63, rb = threadIdx.x >> 6;
  #pragma unroll
  for (int i = 0; i < 16; i++){
    int r = rb + i*4;
    tile[r*65 + c] = f2bf(in[(size_t)(k0 + r)*N + n0 + c]);
  }
  __syncthreads();
  #pragma unroll
  for (int i = 0; i < 16; i++){
    int r = rb + i*4;
    out[(size_t)(n0 + r)*K + k0 + c] = tile[c*65 + r];
  }
}

// ---------------------------------------------------------------------------
// MFMA bf16 GEMM: C[M,N] = A[M,K] @ B[K,N] + bias, B given transposed (N,K).
// A row stride = lda, Bt row stride = ldb, output row stride = N.
// 128x128 block tile, BK=64, 4 waves each 64x64 (4x4 of 16x16x32 MFMA).
// grid = (N/128, M/128). All dims multiples of 128/64 by construction.
// EPI: 0=bf16, 1=bf16 elu+1, 2=bf16 gelu-tanh, 3=f32 residual +=,
//      4=f32 store, 5=f32 clip[-10,2] store.  bias may be nullptr.
// ---------------------------------------------------------------------------
template<int EPI>
__global__ __launch_bounds__(256)
void gemm_bf16_k(const ushort* __restrict__ Ag, const ushort* __restrict__ Bt,
                 const float* __restrict__ bias, ushort* __restrict__ outb,
                 float* __restrict__ outf, int N, int K, int lda, int ldb)
{
  __shared__ ushort As[128*72];   // +8 pad: 2-way LDS banking (free)
  __shared__ ushort Bs[128*72];
  const int tid  = threadIdx.x;
  const int wave = tid >> 6, lane = tid & 63;
  const int q    = lane >> 4, l16 = lane & 15;
  const int bm   = blockIdx.y * 128, bn = blockIdx.x * 128;
  const int wm   = (wave & 1) * 64,  wn = (wave >> 1) * 64;

  f32x4 acc[4][4];
  #pragma unroll
  for (int i = 0; i < 4; i++)
    #pragma unroll
    for (int j = 0; j < 4; j++) acc[i][j] = (f32x4){0.f,0.f,0.f,0.f};

  for (int k0 = 0; k0 < K; k0 += 64){
    #pragma unroll
    for (int i = 0; i < 4; i++){               // 8192 elems per tile, 32/thread
      int e = i*256 + tid;
      int r = e >> 3, c = (e & 7) * 8;
      *(bf16x8*)(As + r*72 + c) = *(const bf16x8*)(Ag + (size_t)(bm + r)*lda + k0 + c);
      *(bf16x8*)(Bs + r*72 + c) = *(const bf16x8*)(Bt + (size_t)(bn + r)*ldb + k0 + c);
    }
    __syncthreads();
    #pragma unroll
    for (int ks = 0; ks < 2; ks++){
      bf16x8 af[4], bfr[4];
      #pragma unroll
      for (int mt = 0; mt < 4; mt++)
        af[mt]  = *(const bf16x8*)(As + (wm + mt*16 + l16)*72 + ks*32 + q*8);
      #pragma unroll
      for (int nt = 0; nt < 4; nt++)
        bfr[nt] = *(const bf16x8*)(Bs + (wn + nt*16 + l16)*72 + ks*32 + q*8);
      #pragma unroll
      for (int mt = 0; mt < 4; mt++)
        #pragma unroll
        for (int nt = 0; nt < 4; nt++)
          acc[mt][nt] = __builtin_amdgcn_mfma_f32_16x16x32_bf16(af[mt], bfr[nt], acc[mt][nt], 0, 0, 0);
    }
    __syncthreads();
  }

  #pragma unroll
  for (int nt = 0; nt < 4; nt++){
    int col  = bn + wn + nt*16 + l16;
    float bv = bias ? bias[col] : 0.f;
    #pragma unroll
    for (int mt = 0; mt < 4; mt++){
      #pragma unroll
      for (int r = 0; r < 4; r++){
        int row   = bm + wm + mt*16 + q*4 + r;
        float v   = acc[mt][nt][r] + bv;
        size_t off = (size_t)row*N + col;
        if      (EPI == 0) outb[off] = f2bf(v);
        else if (EPI == 1) outb[off] = f2bf(v > 0.f ? v + 1.f : __expf(v));
        else if (EPI == 2){
          float g = 0.5f*v*(1.f + tanhf(0.7978845608028654f*(v + 0.044715f*v*v*v)));
          outb[off] = f2bf(g);
        }
        else if (EPI == 3) outf[off] += v;
        else if (EPI == 4) outf[off] = v;
        else if (EPI == 5) outf[off] = fminf(fmaxf(v, -10.f), 2.f);
      }
    }
  }
}

// ---------------------------------------------------------------------------
// LayerNorm fp32 -> bf16. One wave per row (D=768 -> 12 elems/lane).
// TAIL=1: row r maps to physical row (r/TT)*T + CL + (r%TT)  (final-LN slice)
// ---------------------------------------------------------------------------
template<int TAIL>
__global__ __launch_bounds__(256)
void ln_k(const float* __restrict__ x, const float* __restrict__ w,
          const float* __restrict__ b, ushort* __restrict__ out)
{
  int wave = threadIdx.x >> 6, lane = threadIdx.x & 63;
  int row  = blockIdx.x*4 + wave;
  size_t prow;
  if (TAIL){ int bb = row >> 10, t = row & 1023; prow = (size_t)bb*T_ + CL_ + t; }
  else     { prow = row; }
  const float* xr = x + prow*D_;
  float vals[12], s = 0.f, s2 = 0.f;
  #pragma unroll
  for (int j = 0; j < 12; j++){
    float v = xr[j*64 + lane]; vals[j] = v; s += v; s2 += v*v;
  }
  #pragma unroll
  for (int o = 32; o > 0; o >>= 1){ s += __shfl_xor(s, o); s2 += __shfl_xor(s2, o); }
  float m  = s  * (1.f/768.f);
  float var = s2 * (1.f/768.f) - m*m;
  float rs = rsqrtf(var + 1e-5f);
  ushort* orow = out + (size_t)row*D_;
  #pragma unroll
  for (int j = 0; j < 12; j++){
    int e = j*64 + lane;
    orow[e] = f2bf((vals[j] - m)*rs*w[e] + b[e]);
  }
}

// ---------------------------------------------------------------------------
// kvm[b,h] = sum_t k[b,t,h,:]^T v[b,t,h,:]  (64x64), ksum[b,h] = sum_t k.
// grid (BH, 8 k-slices), block 256. Split-K partials via fp32 atomics.
// ---------------------------------------------------------------------------
__global__ __launch_bounds__(256)
void kvm_k(const ushort* __restrict__ kb, const ushort* __restrict__ vb,
           float* __restrict__ kvm, float* __restrict__ ksum)
{
  __shared__ ushort Ks[32*64], Vs[32*64];
  int bh = blockIdx.x, slice = blockIdx.y;
  int b  = bh / H_, h = bh - b*H_;
  int tid = threadIdx.x;
  int e = tid & 63, dbase = (tid >> 6) * 16;
  float acc[16];
  #pragma unroll
  for (int i = 0; i < 16; i++) acc[i] = 0.f;
  float ksacc = 0.f;
  int r = tid >> 3, c = (tid & 7) * 8;
  const size_t base = (size_t)b*T_*D_ + h*HD_;
  for (int t0 = slice*384; t0 < slice*384 + 384; t0 += 32){
    *(bf16x8*)(Ks + r*64 + c) = *(const bf16x8*)(kb + base + (size_t)(t0 + r)*D_ + c);
    *(bf16x8*)(Vs + r*64 + c) = *(const bf16x8*)(vb + base + (size_t)(t0 + r)*D_ + c);
    __syncthreads();
    #pragma unroll 8
    for (int j = 0; j < 32; j++){
      float vv = bf2f(Vs[j*64 + e]);
      #pragma unroll
      for (int d = 0; d < 16; d++) acc[d] += bf2f(Ks[j*64 + dbase + d]) * vv;
    }
    if (tid < 64){
      #pragma unroll 8
      for (int j = 0; j < 32; j++) ksacc += bf2f(Ks[j*64 + tid]);
    }
    __syncthreads();
  }
  float* kv = kvm + (size_t)bh*4096;
  #pragma unroll
  for (int d = 0; d < 16; d++) atomicAdd(&kv[(dbase + d)*64 + e], acc[d]);
  if (tid < 64) atomicAdd(&ksum[bh*64 + tid], ksacc);
}

// ---------------------------------------------------------------------------
// y[b,t,h,:] = (q[b,t,h,:] @ kvm[b,h]) / (q . ksum + 1e-6), bf16 out.
// Safe with yb == qb (each element read exactly by its writer, before write).
// grid (BH, T/32), block 256 = 4 waves x 8 tokens.
// ---------------------------------------------------------------------------
__global__ __launch_bounds__(256)
void y_k(const ushort* __restrict__ qb, const float* __restrict__ kvm,
         const float* __restrict__ ksum, ushort* __restrict__ yb)
{
  __shared__ float kvs[4096];
  int bh = blockIdx.x, b = bh / H_, h = bh - b*H_;
  int tid = threadIdx.x, wave = tid >> 6, lane = tid & 63;
  const float* kvg = kvm + (size_t)bh*4096;
  for (int i = tid; i < 1024; i += 256)
    ((float4*)kvs)[i] = ((const float4*)kvg)[i];
  __syncthreads();
  float ksv = ksum[bh*64 + lane];
  int tbase = blockIdx.y*32 + wave*8;
  for (int i = 0; i < 8; i++){
    int t = tbase + i;
    size_t qoff = ((size_t)b*T_ + t)*D_ + h*HD_ + lane;
    float qd = bf2f(qb[qoff]);
    float dot = qd * ksv;
    #pragma unroll
    for (int o = 32; o > 0; o >>= 1) dot += __shfl_xor(dot, o);
    float z = 1.f / (dot + 1e-6f);
    float a = 0.f;
    #pragma unroll
    for (int d = 0; d < 64; d++)
      a += __shfl(qd, d) * kvs[d*64 + lane];
    yb[qoff] = f2bf(a * z);
  }
}

// ---------------------------------------------------------------------------
// x = concat(context, mq[target_indices]), fp32, float4-vectorized.
// ---------------------------------------------------------------------------
__global__ __launch_bounds__(256)
void build_x_k(const float* __restrict__ ctx, const float* __restrict__ mq,
               const int* __restrict__ tgt, float* __restrict__ x)
{
  int idx = blockIdx.x*256 + threadIdx.x;   // float4 index
  int c  = idx % 192;
  int bt = idx / 192;
  int t  = bt % T_, b = bt / T_;
  float4 v;
  if (t < CL_) v = ((const float4*)ctx)[((size_t)b*CL_ + t)*192 + c];
  else {
    int g = tgt[b*TT_ + (t - CL_)];
    v = ((const float4*)mq)[(size_t)g*192 + c];
  }
  ((float4*)x)[idx] = v;
}

// x[b,t,:] += cb[b,:]  (the collapsed cross-attention)
__global__ __launch_bounds__(256)
void addb_k(float* __restrict__ x, const float* __restrict__ cb)
{
  int idx = blockIdx.x*256 + threadIdx.x;
  int c = idx % 192;
  int b = idx / (192*T_);
  float4 v = ((float4*)x)[idx];
  float4 a = ((const float4*)cb)[b*192 + c];
  v.x += a.x; v.y += a.y; v.z += a.z; v.w += a.w;
  ((float4*)x)[idx] = v;
}

// ---------------------------------------------------------------------------
// Action path (tiny, fp32): a1 = gelu_exact(LN(act @ ad_w1 + b1))
// ---------------------------------------------------------------------------
__global__ __launch_bounds__(256)
void act1_k(const float* __restrict__ act, const float* __restrict__ w1,
            const float* __restrict__ b1, const float* __restrict__ lnw,
            const float* __restrict__ lnb, float* __restrict__ a1)
{
  __shared__ float buf[768];
  __shared__ float red[256];
  int b = blockIdx.x, tid = threadIdx.x;
  const float* ar = act + b*AD_;
  for (int j = tid; j < 768; j += 256){
    float s = b1[j];
    for (int k = 0; k < AD_; k++) s += ar[k]*w1[k*768 + j];
    buf[j] = s;
  }
  __syncthreads();
  red[tid] = buf[tid] + buf[tid+256] + buf[tid+512];
  __syncthreads();
  for (int o = 128; o > 0; o >>= 1){ if (tid < o) red[tid] += red[tid+o]; __syncthreads(); }
  float m = red[0]*(1.f/768.f);
  __syncthreads();
  float v0 = buf[tid]-m, v1 = buf[tid+256]-m, v2 = buf[tid+512]-m;
  red[tid] = v0*v0 + v1*v1 + v2*v2;
  __syncthreads();
  for (int o = 128; o > 0; o >>= 1){ if (tid < o) red[tid] += red[tid+o]; __syncthreads(); }
  float rs = rsqrtf(red[0]*(1.f/768.f) + 1e-5f);
  __syncthreads();
  for (int j = tid; j < 768; j += 256){
    float v = (buf[j]-m)*rs*lnw[j] + lnb[j];
    a1[b*768 + j] = 0.5f*v*(1.f + erff(v*0.70710678118654752f));
  }
}

// emb = a1 @ ad_w2 + b2
__global__ __launch_bounds__(256)
void act2_k(const float* __restrict__ a1, const float* __restrict__ w2,
            const float* __restrict__ b2, float* __restrict__ emb)
{
  __shared__ float inb[768];
  int b = blockIdx.x, tid = threadIdx.x;
  for (int j = tid; j < 768; j += 256) inb[j] = a1[b*768 + j];
  __syncthreads();
  for (int j = tid; j < 768; j += 256){
    float s = b2[j];
    for (int k = 0; k < 768; k++) s += inb[k]*w2[k*768 + j];
    emb[b*768 + j] = s;
  }
}

// cb[l,b,:] = (emb[b] @ a_vw[l] + a_vb[l]) @ a_cw[l] + a_cb[l]
__global__ __launch_bounds__(256)
void cross_k(const float* __restrict__ emb, const float* __restrict__ vw,
             const float* __restrict__ vbias, const float* __restrict__ cw,
             const float* __restrict__ cbias_in, float* __restrict__ cb_out)
{
  __shared__ float inb[768], tmp[768];
  int b = blockIdx.x, l = blockIdx.y, tid = threadIdx.x;
  const float* wv = vw + (size_t)l*768*768;
  const float* wc = cw + (size_t)l*768*768;
  for (int j = tid; j < 768; j += 256) inb[j] = emb[b*768 + j];
  __syncthreads();
  for (int j = tid; j < 768; j += 256){
    float s = vbias[l*768 + j];
    for (int k = 0; k < 768; k++) s += inb[k]*wv[k*768 + j];
    tmp[j] = s;
  }
  __syncthreads();
  for (int j = tid; j < 768; j += 256){
    float s = cbias_in[l*768 + j];
    for (int k = 0; k < 768; k++) s += tmp[k]*wc[k*768 + j];
    cb_out[((size_t)l*B_ + b)*768 + j] = s;
  }
}

// ---------------------------------------------------------------------------
extern "C" void kernel_launch(void* const* d_in, const int* in_sizes, int n_in,
                              void* d_out, int out_size, void* d_ws, size_t ws_size,
                              hipStream_t stream)
{
  (void)in_sizes; (void)n_in; (void)out_size;
  const float* ctx    = (const float*)d_in[0];
  const float* act    = (const float*)d_in[1];
  const int*   tgt    = (const int*)  d_in[2];
  const float* ad_w1  = (const float*)d_in[3];
  const float* ad_b1  = (const float*)d_in[4];
  const float* ad_lnw = (const float*)d_in[5];
  const float* ad_lnb = (const float*)d_in[6];
  const float* ad_w2  = (const float*)d_in[7];
  const float* ad_b2  = (const float*)d_in[8];
  const float* mq     = (const float*)d_in[9];
  // ln1 (10,11), a_qw/qb/kw/kb (12..15) are dead: cross-attn collapses to v@cw+cb
  const float* a_vw   = (const float*)d_in[16];
  const float* a_vb   = (const float*)d_in[17];
  const float* a_cw   = (const float*)d_in[18];
  const float* a_cb   = (const float*)d_in[19];
  const float* ln2_w  = (const float*)d_in[20];
  const float* ln2_b  = (const float*)d_in[21];
  const float* s_qw   = (const float*)d_in[22];
  const float* s_qb   = (const float*)d_in[23];
  const float* s_kw   = (const float*)d_in[24];
  const float* s_kb   = (const float*)d_in[25];
  const float* s_vw   = (const float*)d_in[26];
  const float* s_vb   = (const float*)d_in[27];
  const float* s_cw   = (const float*)d_in[28];
  const float* s_cb   = (const float*)d_in[29];
  const float* ln3_w  = (const float*)d_in[30];
  const float* ln3_b  = (const float*)d_in[31];
  const float* mlp_w1 = (const float*)d_in[32];
  const float* mlp_b1 = (const float*)d_in[33];
  const float* mlp_w2 = (const float*)d_in[34];
  const float* mlp_b2 = (const float*)d_in[35];
  const float* fn_w   = (const float*)d_in[36];
  const float* fn_b   = (const float*)d_in[37];
  const float* mu_w   = (const float*)d_in[38];
  const float* mu_b   = (const float*)d_in[39];
  const float* lv_w   = (const float*)d_in[40];
  const float* lv_b   = (const float*)d_in[41];

  char* ws = (char*)d_ws;
  size_t off = 0;
  auto alloc = [&](size_t bytes) -> char* {
    char* p = ws + off; off += (bytes + 255) & ~(size_t)255; return p;
  };
  const size_t NTOK = (size_t)BT_;            // 24576
  float*  x    = (float*) alloc(NTOK*D_*4);          // 75.5 MB residual stream
  ushort* xn   = (ushort*)alloc(NTOK*D_*2);          // 37.7 MB LN output / pred
  char*   un   = alloc(3*NTOK*D_*2);                 // 113 MB: q,k,v; y->q; h aliases
  ushort* qb   = (ushort*)un;
  ushort* kb   = qb + NTOK*D_;
  ushort* vb   = kb + NTOK*D_;
  ushort* hb   = (ushort*)un;                        // (BT,1536) bf16 chunk, 75.5 MB
  ushort* wl_sq = (ushort*)alloc((size_t)D_*D_*2);   // per-layer converted weights
  ushort* wl_sk = (ushort*)alloc((size_t)D_*D_*2);
  ushort* wl_sv = (ushort*)alloc((size_t)D_*D_*2);
  ushort* wl_sc = (ushort*)alloc((size_t)D_*D_*2);
  ushort* wl_m1 = (ushort*)alloc((size_t)D_*F_*2);
  ushort* wl_m2 = (ushort*)alloc((size_t)F_*D_*2);
  ushort* wt_mu = (ushort*)alloc((size_t)D_*D_*2);
  ushort* wt_lv = (ushort*)alloc((size_t)D_*D_*2);
  float*  kvm   = (float*) alloc((size_t)BH_*HD_*HD_*4);   // 1.5 MB (+ksum adjacent)
  float*  ksum  = (float*) alloc((size_t)BH_*HD_*4);
  float*  cbias = (float*) alloc((size_t)L_*B_*D_*4);
  float*  a1    = (float*) alloc((size_t)B_*D_*4);
  float*  emb   = (float*) alloc((size_t)B_*D_*4);

  if (off > ws_size) return;   // graceful diagnostic: absmax-fail, not a GPU fault

  dim3 blk(256);

  // head weights (used once, convert up front)
  tconv_k<<<dim3(12,12), blk, 0, stream>>>(mu_w, wt_mu, D_, D_);
  tconv_k<<<dim3(12,12), blk, 0, stream>>>(lv_w, wt_lv, D_, D_);

  // action path + collapsed cross-attention biases
  act1_k<<<B_, blk, 0, stream>>>(act, ad_w1, ad_b1, ad_lnw, ad_lnb, a1);
  act2_k<<<B_, blk, 0, stream>>>(a1, ad_w2, ad_b2, emb);
  cross_k<<<dim3(B_, L_), blk, 0, stream>>>(emb, a_vw, a_vb, a_cw, a_cb, cbias);

  // x = concat(context, mq[target_indices])
  build_x_k<<<(BT_*192)/256, blk, 0, stream>>>(ctx, mq, tgt, x);

  const int GY = BT_/128;   // 192
  const int NZ4 = (BH_*HD_*HD_ + BH_*HD_) / 4;   // kvm+ksum float4 count (contiguous)
  for (int i = 0; i < L_; i++){
    // per-layer weight convert+transpose into reused buffers (keeps ws < 256 MiB)
    tconv_k<<<dim3(12,12), blk, 0, stream>>>(s_qw   + (size_t)i*D_*D_, wl_sq, D_, D_);
    tconv_k<<<dim3(12,12), blk, 0, stream>>>(s_kw   + (size_t)i*D_*D_, wl_sk, D_, D_);
    tconv_k<<<dim3(12,12), blk, 0, stream>>>(s_vw   + (size_t)i*D_*D_, wl_sv, D_, D_);
    tconv_k<<<dim3(12,12), blk, 0, stream>>>(s_cw   + (size_t)i*D_*D_, wl_sc, D_, D_);
    tconv_k<<<dim3(48,12), blk, 0, stream>>>(mlp_w1 + (size_t)i*D_*F_, wl_m1, D_, F_);
    tconv_k<<<dim3(12,48), blk, 0, stream>>>(mlp_w2 + (size_t)i*F_*D_, wl_m2, F_, D_);

    addb_k<<<(BT_*192)/256, blk, 0, stream>>>(x, cbias + (size_t)i*B_*D_);

    ln_k<0><<<BT_/4, blk, 0, stream>>>(x, ln2_w + i*D_, ln2_b + i*D_, xn);

    gemm_bf16_k<1><<<dim3(6, GY), blk, 0, stream>>>(xn, wl_sq, s_qb + i*D_, qb, nullptr, D_, D_, D_, D_);
    gemm_bf16_k<1><<<dim3(6, GY), blk, 0, stream>>>(xn, wl_sk, s_kb + i*D_, kb, nullptr, D_, D_, D_, D_);
    gemm_bf16_k<0><<<dim3(6, GY), blk, 0, stream>>>(xn, wl_sv, s_vb + i*D_, vb, nullptr, D_, D_, D_, D_);

    zero_k<<<(NZ4 + 255)/256, blk, 0, stream>>>((float4*)kvm, NZ4);
    kvm_k<<<dim3(BH_, 8), blk, 0, stream>>>(kb, vb, kvm, ksum);
    y_k<<<dim3(BH_, T_/32), blk, 0, stream>>>(qb, kvm, ksum, qb);   // y in-place over q

    gemm_bf16_k<3><<<dim3(6, GY), blk, 0, stream>>>(qb, wl_sc, s_cb + i*D_, nullptr, x, D_, D_, D_, D_);

    ln_k<0><<<BT_/4, blk, 0, stream>>>(x, ln3_w + i*D_, ln3_b + i*D_, xn);
    // MLP in two N=1536 chunks so h fits the 113 MB arena (q,k,v dead here)
    for (int c = 0; c < 2; c++){
      gemm_bf16_k<2><<<dim3(12, GY), blk, 0, stream>>>(
          xn, wl_m1 + (size_t)c*1536*D_, mlp_b1 + (size_t)i*F_ + c*1536,
          hb, nullptr, 1536, D_, D_, D_);
      gemm_bf16_k<3><<<dim3(6, GY), blk, 0, stream>>>(
          hb, wl_m2 + (size_t)c*1536, (c == 0) ? (mlp_b2 + (size_t)i*D_) : nullptr,
          nullptr, x, D_, 1536, 1536, F_);
    }
  }

  // final LN on the prediction slice only
  ln_k<1><<<(B_*TT_)/4, blk, 0, stream>>>(x, fn_w, fn_b, xn);

  // heads
  float* outmu = (float*)d_out;
  float* outlv = outmu + (size_t)B_*TT_*D_;
  gemm_bf16_k<4><<<dim3(6, (B_*TT_)/128), blk, 0, stream>>>(xn, wt_mu, mu_b, nullptr, outmu, D_, D_, D_, D_);
  gemm_bf16_k<5><<<dim3(6, (B_*TT_)/128), blk, 0, stream>>>(xn, wt_lv, lv_b, nullptr, outlv, D_, D_, D_, D_);
}

// Round 3
// 5695.830 us; speedup vs baseline: 1.3613x; 1.3613x over previous
//
#include <hip/hip_runtime.h>
#include <hip/hip_bf16.h>
#include <math.h>

#define B_   8
#define CL_  2048
#define TT_  1024
#define T_   3072      // CL + TT
#define D_   768
#define AD_  320
#define L_   6
#define H_   12
#define F_   3072
#define HD_  64
#define BH_  (B_*H_)
#define BT_  (B_*T_)   // 24576 rows

typedef __bf16 bf16x8 __attribute__((ext_vector_type(8)));
typedef float  f32x4  __attribute__((ext_vector_type(4)));

__device__ __forceinline__ float bf2f(ushort h){
  union { unsigned u; float f; } v; v.u = ((unsigned)h) << 16; return v.f;
}
__device__ __forceinline__ ushort f2bf(float f){
  union { float f; unsigned u; } v; v.f = f;
  unsigned u = v.u;
  return (ushort)((u + 0x7fffu + ((u >> 16) & 1u)) >> 16);  // RNE
}

// async global->LDS, 16B per lane; lds dest must be wave-uniform base (+lane*16)
__device__ __forceinline__ void gl_lds16(const ushort* g, ushort* l){
  __builtin_amdgcn_global_load_lds((__attribute__((address_space(1))) void*)g,
                                   (__attribute__((address_space(3))) void*)l,
                                   16, 0, 0);
}

// ---------------------------------------------------------------------------
__global__ __launch_bounds__(256)
void zero_k(float4* __restrict__ p, int n4)
{
  int i = blockIdx.x*256 + threadIdx.x;
  if (i < n4) p[i] = (float4){0.f,0.f,0.f,0.f};
}

// ---------------------------------------------------------------------------
// Transpose + fp32->bf16 convert:  in (K,N) fp32 row-major -> out (N,K) bf16.
// ---------------------------------------------------------------------------
__global__ __launch_bounds__(256)
void tconv_k(const float* __restrict__ in, ushort* __restrict__ out, int K, int N)
{
  __shared__ ushort tile[64*65];
  int n0 = blockIdx.x*64, k0 = blockIdx.y*64;
  int c  = threadIdx.x & 63, rb = threadIdx.x >> 6;
  #pragma unroll
  for (int i = 0; i < 16; i++){
    int r = rb + i*4;
    tile[r*65 + c] = f2bf(in[(size_t)(k0 + r)*N + n0 + c]);
  }
  __syncthreads();
  #pragma unroll
  for (int i = 0; i < 16; i++){
    int r = rb + i*4;
    out[(size_t)(n0 + r)*K + k0 + c] = tile[c*65 + r];
  }
}

// ---------------------------------------------------------------------------
// MFMA bf16 GEMM, m97-style staging: global_load_lds (16B) into unpadded LDS
// with XOR swizzle. C[M,N] = A[M,K] @ B[K,N] + bias, B transposed (N,K).
// 128x128 tile, BK=64, 4 waves each 64x64. grid (N/128, M/128).
// EPI: 0=bf16, 1=bf16 elu+1, 2=bf16 gelu-tanh(fast), 3=f32 residual +=,
//      4=f32 store, 5=f32 clip[-10,2] store.  bias may be nullptr.
// ---------------------------------------------------------------------------
template<int EPI>
__global__ __launch_bounds__(256)
void gemm_bf16_k(const ushort* __restrict__ Ag, const ushort* __restrict__ Bt,
                 const float* __restrict__ bias, ushort* __restrict__ outb,
                 float* __restrict__ outf, int N, int K, int lda, int ldb)
{
  __shared__ __align__(16) ushort As[128*64];
  __shared__ __align__(16) ushort Bs[128*64];
  const int tid  = threadIdx.x;
  const int wave = tid >> 6, lane = tid & 63;
  const int q    = lane >> 4, l16 = lane & 15;
  const int bm   = blockIdx.y * 128, bn = blockIdx.x * 128;
  const int wm   = (wave & 1) * 64,  wn = (wave >> 1) * 64;
  const int lr   = lane >> 3;                 // row within 8-row chunk
  const int lc   = ((lane & 7) ^ lr) * 8;     // swizzled source column (elems)

  f32x4 acc[4][4];
  #pragma unroll
  for (int i = 0; i < 4; i++)
    #pragma unroll
    for (int j = 0; j < 4; j++) acc[i][j] = (f32x4){0.f,0.f,0.f,0.f};

  for (int k0 = 0; k0 < K; k0 += 64){
    #pragma unroll
    for (int j = 0; j < 4; j++){
      int r0 = wave*8 + j*32;                 // 8-row chunk base (wave-uniform)
      gl_lds16(Ag + (size_t)(bm + r0 + lr)*lda + k0 + lc, As + r0*64);
      gl_lds16(Bt + (size_t)(bn + r0 + lr)*ldb + k0 + lc, Bs + r0*64);
    }
    __syncthreads();
    #pragma unroll
    for (int ks = 0; ks < 2; ks++){
      const int sx = (((ks*4 + q) ^ (l16 & 7)) * 8);   // de-swizzled chunk
      bf16x8 af[4], bfr[4];
      #pragma unroll
      for (int mt = 0; mt < 4; mt++)
        af[mt]  = *(const bf16x8*)(As + (wm + mt*16 + l16)*64 + sx);
      #pragma unroll
      for (int nt = 0; nt < 4; nt++)
        bfr[nt] = *(const bf16x8*)(Bs + (wn + nt*16 + l16)*64 + sx);
      #pragma unroll
      for (int mt = 0; mt < 4; mt++)
        #pragma unroll
        for (int nt = 0; nt < 4; nt++)
          acc[mt][nt] = __builtin_amdgcn_mfma_f32_16x16x32_bf16(af[mt], bfr[nt], acc[mt][nt], 0, 0, 0);
    }
    __syncthreads();
  }

  #pragma unroll
  for (int nt = 0; nt < 4; nt++){
    int col  = bn + wn + nt*16 + l16;
    float bv = bias ? bias[col] : 0.f;
    #pragma unroll
    for (int mt = 0; mt < 4; mt++){
      #pragma unroll
      for (int r = 0; r < 4; r++){
        int row   = bm + wm + mt*16 + q*4 + r;
        float v   = acc[mt][nt][r] + bv;
        size_t off = (size_t)row*N + col;
        if      (EPI == 0) outb[off] = f2bf(v);
        else if (EPI == 1) outb[off] = f2bf(v > 0.f ? v + 1.f : __expf(v));
        else if (EPI == 2){
          // gelu-tanh via exp: g = v - v/(exp(2u)+1), u = 0.79788456(v+0.044715v^3)
          float t = __expf(1.5957691216057308f*v + 0.0713548162726009f*v*v*v);
          outb[off] = f2bf(v - v/(t + 1.f));
        }
        else if (EPI == 3) outf[off] += v;
        else if (EPI == 4) outf[off] = v;
        else if (EPI == 5) outf[off] = fminf(fmaxf(v, -10.f), 2.f);
      }
    }
  }
}

// ---------------------------------------------------------------------------
// y = (q @ kvm) * 1/(q.ksum + 1e-6) via MFMA. Per (b,h): A = q (T x 64),
// B^T rows: 0..63 = kvm^T (bf16), 64 = ksum, 65..79 = 0. N=80, col 64 = dot.
// grid (BH, T/128), block 256 (4 waves x 32 rows). Safe in-place (yb==qb).
// ---------------------------------------------------------------------------
__global__ __launch_bounds__(256)
void y_mfma_k(const ushort* __restrict__ qb, const float* __restrict__ kvm,
              const float* __restrict__ ksum, ushort* __restrict__ yb)
{
  __shared__ __align__(16) ushort Qs[128*72];
  __shared__ __align__(16) ushort Bs[80*72];
  int bh = blockIdx.x, b = bh / H_, h = bh - b*H_;
  int bm = blockIdx.y * 128;
  int tid = threadIdx.x, wave = tid >> 6, lane = tid & 63;
  int q = lane >> 4, l16 = lane & 15;

  const float* kvg = kvm + (size_t)bh*4096;
  #pragma unroll
  for (int rep = 0; rep < 16; rep++){
    int idx = rep*256 + tid;              // d*64+e, coalesced read
    int d = idx >> 6, e = idx & 63;
    Bs[e*72 + d] = f2bf(kvg[idx]);        // transpose into B^T[n=e][k=d]
  }
  if (tid < 64) Bs[64*72 + tid] = f2bf(ksum[bh*64 + tid]);
  for (int idx = tid; idx < 15*64; idx += 256){
    int r = 65 + idx/64, c = idx & 63;
    Bs[r*72 + c] = 0;
  }
  const size_t qbase = ((size_t)b*T_ + bm)*D_ + h*HD_;
  #pragma unroll
  for (int i = 0; i < 4; i++){
    int e = i*256 + tid;
    int r = e >> 3, c = (e & 7)*8;
    *(bf16x8*)(Qs + r*72 + c) = *(const bf16x8*)(qb + qbase + (size_t)r*D_ + c);
  }
  __syncthreads();

  int wm = wave*32;
  f32x4 acc[2][5];
  #pragma unroll
  for (int i = 0; i < 2; i++)
    #pragma unroll
    for (int j = 0; j < 5; j++) acc[i][j] = (f32x4){0.f,0.f,0.f,0.f};

  #pragma unroll
  for (int ks = 0; ks < 2; ks++){
    bf16x8 af[2], bfr[5];
    #pragma unroll
    for (int mt = 0; mt < 2; mt++)
      af[mt]  = *(const bf16x8*)(Qs + (wm + mt*16 + l16)*72 + ks*32 + q*8);
    #pragma unroll
    for (int nt = 0; nt < 5; nt++)
      bfr[nt] = *(const bf16x8*)(Bs + (nt*16 + l16)*72 + ks*32 + q*8);
    #pragma unroll
    for (int mt = 0; mt < 2; mt++)
      #pragma unroll
      for (int nt = 0; nt < 5; nt++)
        acc[mt][nt] = __builtin_amdgcn_mfma_f32_16x16x32_bf16(af[mt], bfr[nt], acc[mt][nt], 0, 0, 0);
  }

  #pragma unroll
  for (int mt = 0; mt < 2; mt++){
    #pragma unroll
    for (int r = 0; r < 4; r++){
      float d0 = __shfl(acc[mt][4][r], lane & 48);   // col 64 lives at l16==0
      float z  = 1.f / (d0 + 1e-6f);
      int row  = bm + wm + mt*16 + q*4 + r;
      size_t obase = ((size_t)b*T_ + row)*D_ + h*HD_;
      #pragma unroll
      for (int nt = 0; nt < 4; nt++)
        yb[obase + nt*16 + l16] = f2bf(acc[mt][nt][r] * z);
    }
  }
}

// ---------------------------------------------------------------------------
// Fused: x += cb[b];  xn = LN(x)  (bf16). One wave per row.
// ---------------------------------------------------------------------------
__global__ __launch_bounds__(256)
void ln_add_k(float* __restrict__ x, const float* __restrict__ cb,
              const float* __restrict__ w, const float* __restrict__ b,
              ushort* __restrict__ out)
{
  int wave = threadIdx.x >> 6, lane = threadIdx.x & 63;
  int row  = blockIdx.x*4 + wave;
  int bidx = row / T_;
  float* xr = x + (size_t)row*D_;
  const float* cbr = cb + (size_t)bidx*D_;
  float vals[12], s = 0.f, s2 = 0.f;
  #pragma unroll
  for (int j = 0; j < 12; j++){
    int e = j*64 + lane;
    float v = xr[e] + cbr[e];
    xr[e] = v;
    vals[j] = v; s += v; s2 += v*v;
  }
  #pragma unroll
  for (int o = 32; o > 0; o >>= 1){ s += __shfl_xor(s, o); s2 += __shfl_xor(s2, o); }
  float m   = s  * (1.f/768.f);
  float var = s2 * (1.f/768.f) - m*m;
  float rs  = rsqrtf(var + 1e-5f);
  ushort* orow = out + (size_t)row*D_;
  #pragma unroll
  for (int j = 0; j < 12; j++){
    int e = j*64 + lane;
    orow[e] = f2bf((vals[j] - m)*rs*w[e] + b[e]);
  }
}

// ---------------------------------------------------------------------------
// LayerNorm fp32 -> bf16. TAIL=1: row -> (r/TT)*T + CL + (r%TT)
// ---------------------------------------------------------------------------
template<int TAIL>
__global__ __launch_bounds__(256)
void ln_k(const float* __restrict__ x, const float* __restrict__ w,
          const float* __restrict__ b, ushort* __restrict__ out)
{
  int wave = threadIdx.x >> 6, lane = threadIdx.x & 63;
  int row  = blockIdx.x*4 + wave;
  size_t prow;
  if (TAIL){ int bb = row >> 10, t = row & 1023; prow = (size_t)bb*T_ + CL_ + t; }
  else     { prow = row; }
  const float* xr = x + prow*D_;
  float vals[12], s = 0.f, s2 = 0.f;
  #pragma unroll
  for (int j = 0; j < 12; j++){
    float v = xr[j*64 + lane]; vals[j] = v; s += v; s2 += v*v;
  }
  #pragma unroll
  for (int o = 32; o > 0; o >>= 1){ s += __shfl_xor(s, o); s2 += __shfl_xor(s2, o); }
  float m  = s  * (1.f/768.f);
  float var = s2 * (1.f/768.f) - m*m;
  float rs = rsqrtf(var + 1e-5f);
  ushort* orow = out + (size_t)row*D_;
  #pragma unroll
  for (int j = 0; j < 12; j++){
    int e = j*64 + lane;
    orow[e] = f2bf((vals[j] - m)*rs*w[e] + b[e]);
  }
}

// ---------------------------------------------------------------------------
// kvm[b,h] = sum_t k^T v (64x64), ksum = sum_t k. Split-K atomics.
// ---------------------------------------------------------------------------
__global__ __launch_bounds__(256)
void kvm_k(const ushort* __restrict__ kb, const ushort* __restrict__ vb,
           float* __restrict__ kvm, float* __restrict__ ksum)
{
  __shared__ ushort Ks[32*64], Vs[32*64];
  int bh = blockIdx.x, slice = blockIdx.y;
  int b  = bh / H_, h = bh - b*H_;
  int tid = threadIdx.x;
  int e = tid & 63, dbase = (tid >> 6) * 16;
  float acc[16];
  #pragma unroll
  for (int i = 0; i < 16; i++) acc[i] = 0.f;
  float ksacc = 0.f;
  int r = tid >> 3, c = (tid & 7) * 8;
  const size_t base = (size_t)b*T_*D_ + h*HD_;
  for (int t0 = slice*384; t0 < slice*384 + 384; t0 += 32){
    *(bf16x8*)(Ks + r*64 + c) = *(const bf16x8*)(kb + base + (size_t)(t0 + r)*D_ + c);
    *(bf16x8*)(Vs + r*64 + c) = *(const bf16x8*)(vb + base + (size_t)(t0 + r)*D_ + c);
    __syncthreads();
    #pragma unroll 8
    for (int j = 0; j < 32; j++){
      float vv = bf2f(Vs[j*64 + e]);
      #pragma unroll
      for (int d = 0; d < 16; d++) acc[d] += bf2f(Ks[j*64 + dbase + d]) * vv;
    }
    if (tid < 64){
      #pragma unroll 8
      for (int j = 0; j < 32; j++) ksacc += bf2f(Ks[j*64 + tid]);
    }
    __syncthreads();
  }
  float* kv = kvm + (size_t)bh*4096;
  #pragma unroll
  for (int d = 0; d < 16; d++) atomicAdd(&kv[(dbase + d)*64 + e], acc[d]);
  if (tid < 64) atomicAdd(&ksum[bh*64 + tid], ksacc);
}

// ---------------------------------------------------------------------------
__global__ __launch_bounds__(256)
void build_x_k(const float* __restrict__ ctx, const float* __restrict__ mq,
               const int* __restrict__ tgt, float* __restrict__ x)
{
  int idx = blockIdx.x*256 + threadIdx.x;   // float4 index
  int c  = idx % 192;
  int bt = idx / 192;
  int t  = bt % T_, b = bt / T_;
  float4 v;
  if (t < CL_) v = ((const float4*)ctx)[((size_t)b*CL_ + t)*192 + c];
  else {
    int g = tgt[b*TT_ + (t - CL_)];
    v = ((const float4*)mq)[(size_t)g*192 + c];
  }
  ((float4*)x)[idx] = v;
}

// ---------------------------------------------------------------------------
__global__ __launch_bounds__(256)
void act1_k(const float* __restrict__ act, const float* __restrict__ w1,
            const float* __restrict__ b1, const float* __restrict__ lnw,
            const float* __restrict__ lnb, float* __restrict__ a1)
{
  __shared__ float buf[768];
  __shared__ float red[256];
  int b = blockIdx.x, tid = threadIdx.x;
  const float* ar = act + b*AD_;
  for (int j = tid; j < 768; j += 256){
    float s = b1[j];
    for (int k = 0; k < AD_; k++) s += ar[k]*w1[k*768 + j];
    buf[j] = s;
  }
  __syncthreads();
  red[tid] = buf[tid] + buf[tid+256] + buf[tid+512];
  __syncthreads();
  for (int o = 128; o > 0; o >>= 1){ if (tid < o) red[tid] += red[tid+o]; __syncthreads(); }
  float m = red[0]*(1.f/768.f);
  __syncthreads();
  float v0 = buf[tid]-m, v1 = buf[tid+256]-m, v2 = buf[tid+512]-m;
  red[tid] = v0*v0 + v1*v1 + v2*v2;
  __syncthreads();
  for (int o = 128; o > 0; o >>= 1){ if (tid < o) red[tid] += red[tid+o]; __syncthreads(); }
  float rs = rsqrtf(red[0]*(1.f/768.f) + 1e-5f);
  __syncthreads();
  for (int j = tid; j < 768; j += 256){
    float v = (buf[j]-m)*rs*lnw[j] + lnb[j];
    a1[b*768 + j] = 0.5f*v*(1.f + erff(v*0.70710678118654752f));
  }
}

__global__ __launch_bounds__(256)
void act2_k(const float* __restrict__ a1, const float* __restrict__ w2,
            const float* __restrict__ b2, float* __restrict__ emb)
{
  __shared__ float inb[768];
  int b = blockIdx.x, tid = threadIdx.x;
  for (int j = tid; j < 768; j += 256) inb[j] = a1[b*768 + j];
  __syncthreads();
  for (int j = tid; j < 768; j += 256){
    float s = b2[j];
    for (int k = 0; k < 768; k++) s += inb[k]*w2[k*768 + j];
    emb[b*768 + j] = s;
  }
}

__global__ __launch_bounds__(256)
void cross_k(const float* __restrict__ emb, const float* __restrict__ vw,
             const float* __restrict__ vbias, const float* __restrict__ cw,
             const float* __restrict__ cbias_in, float* __restrict__ cb_out)
{
  __shared__ float inb[768], tmp[768];
  int b = blockIdx.x, l = blockIdx.y, tid = threadIdx.x;
  const float* wv = vw + (size_t)l*768*768;
  const float* wc = cw + (size_t)l*768*768;
  for (int j = tid; j < 768; j += 256) inb[j] = emb[b*768 + j];
  __syncthreads();
  for (int j = tid; j < 768; j += 256){
    float s = vbias[l*768 + j];
    for (int k = 0; k < 768; k++) s += inb[k]*wv[k*768 + j];
    tmp[j] = s;
  }
  __syncthreads();
  for (int j = tid; j < 768; j += 256){
    float s = cbias_in[l*768 + j];
    for (int k = 0; k < 768; k++) s += tmp[k]*wc[k*768 + j];
    cb_out[((size_t)l*B_ + b)*768 + j] = s;
  }
}

// ---------------------------------------------------------------------------
extern "C" void kernel_launch(void* const* d_in, const int* in_sizes, int n_in,
                              void* d_out, int out_size, void* d_ws, size_t ws_size,
                              hipStream_t stream)
{
  (void)in_sizes; (void)n_in; (void)out_size;
  const float* ctx    = (const float*)d_in[0];
  const float* act    = (const float*)d_in[1];
  const int*   tgt    = (const int*)  d_in[2];
  const float* ad_w1  = (const float*)d_in[3];
  const float* ad_b1  = (const float*)d_in[4];
  const float* ad_lnw = (const float*)d_in[5];
  const float* ad_lnb = (const float*)d_in[6];
  const float* ad_w2  = (const float*)d_in[7];
  const float* ad_b2  = (const float*)d_in[8];
  const float* mq     = (const float*)d_in[9];
  // ln1 (10,11), a_qw/qb/kw/kb (12..15) dead: cross-attn collapses to v@cw+cb
  const float* a_vw   = (const float*)d_in[16];
  const float* a_vb   = (const float*)d_in[17];
  const float* a_cw   = (const float*)d_in[18];
  const float* a_cb   = (const float*)d_in[19];
  const float* ln2_w  = (const float*)d_in[20];
  const float* ln2_b  = (const float*)d_in[21];
  const float* s_qw   = (const float*)d_in[22];
  const float* s_qb   = (const float*)d_in[23];
  const float* s_kw   = (const float*)d_in[24];
  const float* s_kb   = (const float*)d_in[25];
  const float* s_vw   = (const float*)d_in[26];
  const float* s_vb   = (const float*)d_in[27];
  const float* s_cw   = (const float*)d_in[28];
  const float* s_cb   = (const float*)d_in[29];
  const float* ln3_w  = (const float*)d_in[30];
  const float* ln3_b  = (const float*)d_in[31];
  const float* mlp_w1 = (const float*)d_in[32];
  const float* mlp_b1 = (const float*)d_in[33];
  const float* mlp_w2 = (const float*)d_in[34];
  const float* mlp_b2 = (const float*)d_in[35];
  const float* fn_w   = (const float*)d_in[36];
  const float* fn_b   = (const float*)d_in[37];
  const float* mu_w   = (const float*)d_in[38];
  const float* mu_b   = (const float*)d_in[39];
  const float* lv_w   = (const float*)d_in[40];
  const float* lv_b   = (const float*)d_in[41];

  char* ws = (char*)d_ws;
  size_t off = 0;
  auto alloc = [&](size_t bytes) -> char* {
    char* p = ws + off; off += (bytes + 255) & ~(size_t)255; return p;
  };
  const size_t NTOK = (size_t)BT_;            // 24576
  float*  x    = (float*) alloc(NTOK*D_*4);          // 75.5 MB residual
  ushort* xn   = (ushort*)alloc(NTOK*D_*2);          // 37.7 MB LN out / pred
  char*   un   = alloc(3*NTOK*D_*2);                 // 113 MB: q,k,v; y->q; h alias
  ushort* qb   = (ushort*)un;
  ushort* kb   = qb + NTOK*D_;
  ushort* vb   = kb + NTOK*D_;
  ushort* hb   = (ushort*)un;                        // (BT,1536) bf16 chunk
  ushort* wl_sq = (ushort*)alloc((size_t)D_*D_*2);
  ushort* wl_sk = (ushort*)alloc((size_t)D_*D_*2);
  ushort* wl_sv = (ushort*)alloc((size_t)D_*D_*2);
  ushort* wl_sc = (ushort*)alloc((size_t)D_*D_*2);
  ushort* wl_m1 = (ushort*)alloc((size_t)D_*F_*2);
  ushort* wl_m2 = (ushort*)alloc((size_t)F_*D_*2);
  ushort* wt_mu = (ushort*)alloc((size_t)D_*D_*2);
  ushort* wt_lv = (ushort*)alloc((size_t)D_*D_*2);
  float*  kvm   = (float*) alloc((size_t)BH_*HD_*HD_*4);
  float*  ksum  = (float*) alloc((size_t)BH_*HD_*4);
  float*  cbias = (float*) alloc((size_t)L_*B_*D_*4);
  float*  a1    = (float*) alloc((size_t)B_*D_*4);
  float*  emb   = (float*) alloc((size_t)B_*D_*4);

  if (off > ws_size) return;

  dim3 blk(256);

  tconv_k<<<dim3(12,12), blk, 0, stream>>>(mu_w, wt_mu, D_, D_);
  tconv_k<<<dim3(12,12), blk, 0, stream>>>(lv_w, wt_lv, D_, D_);

  act1_k<<<B_, blk, 0, stream>>>(act, ad_w1, ad_b1, ad_lnw, ad_lnb, a1);
  act2_k<<<B_, blk, 0, stream>>>(a1, ad_w2, ad_b2, emb);
  cross_k<<<dim3(B_, L_), blk, 0, stream>>>(emb, a_vw, a_vb, a_cw, a_cb, cbias);

  build_x_k<<<(BT_*192)/256, blk, 0, stream>>>(ctx, mq, tgt, x);

  const int GY = BT_/128;   // 192
  const int NZ4 = (BH_*HD_*HD_ + BH_*HD_) / 4;
  for (int i = 0; i < L_; i++){
    tconv_k<<<dim3(12,12), blk, 0, stream>>>(s_qw   + (size_t)i*D_*D_, wl_sq, D_, D_);
    tconv_k<<<dim3(12,12), blk, 0, stream>>>(s_kw   + (size_t)i*D_*D_, wl_sk, D_, D_);
    tconv_k<<<dim3(12,12), blk, 0, stream>>>(s_vw   + (size_t)i*D_*D_, wl_sv, D_, D_);
    tconv_k<<<dim3(12,12), blk, 0, stream>>>(s_cw   + (size_t)i*D_*D_, wl_sc, D_, D_);
    tconv_k<<<dim3(48,12), blk, 0, stream>>>(mlp_w1 + (size_t)i*D_*F_, wl_m1, D_, F_);
    tconv_k<<<dim3(12,48), blk, 0, stream>>>(mlp_w2 + (size_t)i*F_*D_, wl_m2, F_, D_);

    // fused: x += cbias_i; xn = LN2(x)
    ln_add_k<<<BT_/4, blk, 0, stream>>>(x, cbias + (size_t)i*B_*D_,
                                        ln2_w + i*D_, ln2_b + i*D_, xn);

    gemm_bf16_k<1><<<dim3(6, GY), blk, 0, stream>>>(xn, wl_sq, s_qb + i*D_, qb, nullptr, D_, D_, D_, D_);
    gemm_bf16_k<1><<<dim3(6, GY), blk, 0, stream>>>(xn, wl_sk, s_kb + i*D_, kb, nullptr, D_, D_, D_, D_);
    gemm_bf16_k<0><<<dim3(6, GY), blk, 0, stream>>>(xn, wl_sv, s_vb + i*D_, vb, nullptr, D_, D_, D_, D_);

    zero_k<<<(NZ4 + 255)/256, blk, 0, stream>>>((float4*)kvm, NZ4);
    kvm_k<<<dim3(BH_, 8), blk, 0, stream>>>(kb, vb, kvm, ksum);
    y_mfma_k<<<dim3(BH_, T_/128), blk, 0, stream>>>(qb, kvm, ksum, qb);  // in-place

    gemm_bf16_k<3><<<dim3(6, GY), blk, 0, stream>>>(qb, wl_sc, s_cb + i*D_, nullptr, x, D_, D_, D_, D_);

    ln_k<0><<<BT_/4, blk, 0, stream>>>(x, ln3_w + i*D_, ln3_b + i*D_, xn);
    for (int c = 0; c < 2; c++){
      gemm_bf16_k<2><<<dim3(12, GY), blk, 0, stream>>>(
          xn, wl_m1 + (size_t)c*1536*D_, mlp_b1 + (size_t)i*F_ + c*1536,
          hb, nullptr, 1536, D_, D_, D_);
      gemm_bf16_k<3><<<dim3(6, GY), blk, 0, stream>>>(
          hb, wl_m2 + (size_t)c*1536, (c == 0) ? (mlp_b2 + (size_t)i*D_) : nullptr,
          nullptr, x, D_, 1536, 1536, F_);
    }
  }

  ln_k<1><<<(B_*TT_)/4, blk, 0, stream>>>(x, fn_w, fn_b, xn);

  float* outmu = (float*)d_out;
  float* outlv = outmu + (size_t)B_*TT_*D_;
  gemm_bf16_k<4><<<dim3(6, (B_*TT_)/128), blk, 0, stream>>>(xn, wt_mu, mu_b, nullptr, outmu, D_, D_, D_, D_);
  gemm_bf16_k<5><<<dim3(6, (B_*TT_)/128), blk, 0, stream>>>(xn, wt_lv, lv_b, nullptr, outlv, D_, D_, D_, D_);
}

// Round 4
// 4964.383 us; speedup vs baseline: 1.5619x; 1.1473x over previous
//
#include <hip/hip_runtime.h>
#include <hip/hip_bf16.h>
#include <math.h>

#define B_   8
#define CL_  2048
#define TT_  1024
#define T_   3072      // CL + TT
#define D_   768
#define AD_  320
#define L_   6
#define H_   12
#define F_   3072
#define HD_  64
#define BH_  (B_*H_)
#define BT_  (B_*T_)   // 24576 rows

typedef __bf16 bf16x8 __attribute__((ext_vector_type(8)));
typedef float  f32x4  __attribute__((ext_vector_type(4)));

__device__ __forceinline__ float bf2f(ushort h){
  union { unsigned u; float f; } v; v.u = ((unsigned)h) << 16; return v.f;
}
__device__ __forceinline__ ushort f2bf(float f){
  union { float f; unsigned u; } v; v.f = f;
  unsigned u = v.u;
  return (ushort)((u + 0x7fffu + ((u >> 16) & 1u)) >> 16);  // RNE
}

// async global->LDS, 16B per lane; lds dest must be wave-uniform base (+lane*16)
__device__ __forceinline__ void gl_lds16(const ushort* g, ushort* l){
  __builtin_amdgcn_global_load_lds((__attribute__((address_space(1))) void*)g,
                                   (__attribute__((address_space(3))) void*)l,
                                   16, 0, 0);
}

// ---------------------------------------------------------------------------
__global__ __launch_bounds__(256)
void zero_k(float4* __restrict__ p, int n4)
{
  int i = blockIdx.x*256 + threadIdx.x;
  if (i < n4) p[i] = (float4){0.f,0.f,0.f,0.f};
}

// ---------------------------------------------------------------------------
// Transpose + fp32->bf16 convert core: in (K,N) fp32 -> out (N,K) bf16.
// ---------------------------------------------------------------------------
__device__ __forceinline__ void tconv_body(const float* in, ushort* out,
                                           int K, int N, int k0, int n0)
{
  __shared__ ushort tile[64*65];
  int c  = threadIdx.x & 63, rb = threadIdx.x >> 6;
  #pragma unroll
  for (int i = 0; i < 16; i++){
    int r = rb + i*4;
    tile[r*65 + c] = f2bf(in[(size_t)(k0 + r)*N + n0 + c]);
  }
  __syncthreads();
  #pragma unroll
  for (int i = 0; i < 16; i++){
    int r = rb + i*4;
    out[(size_t)(n0 + r)*K + k0 + c] = tile[c*65 + r];
  }
}

__global__ __launch_bounds__(256)
void tconv_k(const float* __restrict__ in, ushort* __restrict__ out, int K, int N)
{
  tconv_body(in, out, K, N, blockIdx.y*64, blockIdx.x*64);
}

// 4 D x D weights (q,k,v,c) in one dispatch; out contiguous 4x(768,768)
__global__ __launch_bounds__(256)
void tconv4_k(const float* __restrict__ s0, const float* __restrict__ s1,
              const float* __restrict__ s2, const float* __restrict__ s3,
              ushort* __restrict__ out)
{
  int z = blockIdx.z;
  const float* in = (z == 0) ? s0 : (z == 1) ? s1 : (z == 2) ? s2 : s3;
  tconv_body(in, out + (size_t)z*D_*D_, D_, D_, blockIdx.y*64, blockIdx.x*64);
}

// z=0: mlp_w1 (768,3072); z=1: mlp_w2 (3072,768). grid (48,12,2).
__global__ __launch_bounds__(256)
void tconvM_k(const float* __restrict__ w1, ushort* __restrict__ o1,
              const float* __restrict__ w2, ushort* __restrict__ o2)
{
  if (blockIdx.z == 0)
    tconv_body(w1, o1, D_, F_, blockIdx.y*64, blockIdx.x*64);
  else
    tconv_body(w2, o2, F_, D_, blockIdx.x*64, blockIdx.y*64);
}

// ---------------------------------------------------------------------------
// MFMA bf16 GEMM, global_load_lds staging with XOR swizzle.
// C[M,N] = A[M,K] @ B[K,N] + bias, B transposed (N,K). 128x128 tile, BK=64.
// grid (N/128, M/128).
// EPI: 0=bf16, 1=bf16 elu+1, 2=bf16 gelu-tanh(fast), 3=f32 residual +=,
//      4=f32 store, 5=f32 clip, 6=heads mu|lv (N=1536), 7=qkv (N=2304).
// ---------------------------------------------------------------------------
template<int EPI>
__global__ __launch_bounds__(256)
void gemm_bf16_k(const ushort* __restrict__ Ag, const ushort* __restrict__ Bt,
                 const float* __restrict__ bias, const float* __restrict__ bias2,
                 const float* __restrict__ bias3, ushort* __restrict__ outb,
                 float* __restrict__ outf, int N, int K, int lda, int ldb)
{
  __shared__ __align__(16) ushort As[128*64];
  __shared__ __align__(16) ushort Bs[128*64];
  const int tid  = threadIdx.x;
  const int wave = tid >> 6, lane = tid & 63;
  const int q    = lane >> 4, l16 = lane & 15;
  const int bm   = blockIdx.y * 128, bn = blockIdx.x * 128;
  const int wm   = (wave & 1) * 64,  wn = (wave >> 1) * 64;
  const int lr   = lane >> 3;                 // row within 8-row chunk
  const int lc   = ((lane & 7) ^ lr) * 8;     // swizzled source column (elems)

  f32x4 acc[4][4];
  #pragma unroll
  for (int i = 0; i < 4; i++)
    #pragma unroll
    for (int j = 0; j < 4; j++) acc[i][j] = (f32x4){0.f,0.f,0.f,0.f};

  for (int k0 = 0; k0 < K; k0 += 64){
    #pragma unroll
    for (int j = 0; j < 4; j++){
      int r0 = wave*8 + j*32;                 // 8-row chunk base (wave-uniform)
      gl_lds16(Ag + (size_t)(bm + r0 + lr)*lda + k0 + lc, As + r0*64);
      gl_lds16(Bt + (size_t)(bn + r0 + lr)*ldb + k0 + lc, Bs + r0*64);
    }
    __syncthreads();
    #pragma unroll
    for (int ks = 0; ks < 2; ks++){
      const int sx = (((ks*4 + q) ^ (l16 & 7)) * 8);   // de-swizzled chunk
      bf16x8 af[4], bfr[4];
      #pragma unroll
      for (int mt = 0; mt < 4; mt++)
        af[mt]  = *(const bf16x8*)(As + (wm + mt*16 + l16)*64 + sx);
      #pragma unroll
      for (int nt = 0; nt < 4; nt++)
        bfr[nt] = *(const bf16x8*)(Bs + (wn + nt*16 + l16)*64 + sx);
      #pragma unroll
      for (int mt = 0; mt < 4; mt++)
        #pragma unroll
        for (int nt = 0; nt < 4; nt++)
          acc[mt][nt] = __builtin_amdgcn_mfma_f32_16x16x32_bf16(af[mt], bfr[nt], acc[mt][nt], 0, 0, 0);
    }
    __syncthreads();
  }

  #pragma unroll
  for (int nt = 0; nt < 4; nt++){
    int col = bn + wn + nt*16 + l16;
    int seg = 0, cc = col;
    if (EPI == 6 || EPI == 7){
      seg = (col >= 1536) ? 2 : (col >= 768) ? 1 : 0;
      cc  = col - seg*768;
    }
    float bv;
    if      (EPI == 7) bv = (seg == 0) ? bias[cc] : (seg == 1) ? bias2[cc] : bias3[cc];
    else if (EPI == 6) bv = seg ? bias2[cc] : bias[cc];
    else               bv = bias ? bias[col] : 0.f;
    #pragma unroll
    for (int mt = 0; mt < 4; mt++){
      #pragma unroll
      for (int r = 0; r < 4; r++){
        int row = bm + wm + mt*16 + q*4 + r;
        float v = acc[mt][nt][r] + bv;
        if (EPI == 7){
          float o = (seg < 2) ? (v > 0.f ? v + 1.f : __expf(v)) : v;  // elu+1 on q,k
          outb[(size_t)seg*((size_t)BT_*D_) + (size_t)row*D_ + cc] = f2bf(o);
        } else if (EPI == 6){
          size_t o = (size_t)seg*((size_t)B_*TT_*D_) + (size_t)row*D_ + cc;
          outf[o] = seg ? fminf(fmaxf(v, -10.f), 2.f) : v;
        } else {
          size_t off = (size_t)row*N + col;
          if      (EPI == 0) outb[off] = f2bf(v);
          else if (EPI == 1) outb[off] = f2bf(v > 0.f ? v + 1.f : __expf(v));
          else if (EPI == 2){
            float t = __expf(1.5957691216057308f*v + 0.0713548162726009f*v*v*v);
            outb[off] = f2bf(v - v/(t + 1.f));
          }
          else if (EPI == 3) outf[off] += v;
          else if (EPI == 4) outf[off] = v;
          else if (EPI == 5) outf[off] = fminf(fmaxf(v, -10.f), 2.f);
        }
      }
    }
  }
}

// ---------------------------------------------------------------------------
// y = (q @ kvm) * 1/(q.ksum + 1e-6) via MFMA. In-place safe (yb==qb).
// ---------------------------------------------------------------------------
__global__ __launch_bounds__(256)
void y_mfma_k(const ushort* __restrict__ qb, const float* __restrict__ kvm,
              const float* __restrict__ ksum, ushort* __restrict__ yb)
{
  __shared__ __align__(16) ushort Qs[128*72];
  __shared__ __align__(16) ushort Bs[80*72];
  int bh = blockIdx.x, b = bh / H_, h = bh - b*H_;
  int bm = blockIdx.y * 128;
  int tid = threadIdx.x, wave = tid >> 6, lane = tid & 63;
  int q = lane >> 4, l16 = lane & 15;

  const float* kvg = kvm + (size_t)bh*4096;
  #pragma unroll
  for (int rep = 0; rep < 16; rep++){
    int idx = rep*256 + tid;
    int d = idx >> 6, e = idx & 63;
    Bs[e*72 + d] = f2bf(kvg[idx]);
  }
  if (tid < 64) Bs[64*72 + tid] = f2bf(ksum[bh*64 + tid]);
  for (int idx = tid; idx < 15*64; idx += 256){
    int r = 65 + idx/64, c = idx & 63;
    Bs[r*72 + c] = 0;
  }
  const size_t qbase = ((size_t)b*T_ + bm)*D_ + h*HD_;
  #pragma unroll
  for (int i = 0; i < 4; i++){
    int e = i*256 + tid;
    int r = e >> 3, c = (e & 7)*8;
    *(bf16x8*)(Qs + r*72 + c) = *(const bf16x8*)(qb + qbase + (size_t)r*D_ + c);
  }
  __syncthreads();

  int wm = wave*32;
  f32x4 acc[2][5];
  #pragma unroll
  for (int i = 0; i < 2; i++)
    #pragma unroll
    for (int j = 0; j < 5; j++) acc[i][j] = (f32x4){0.f,0.f,0.f,0.f};

  #pragma unroll
  for (int ks = 0; ks < 2; ks++){
    bf16x8 af[2], bfr[5];
    #pragma unroll
    for (int mt = 0; mt < 2; mt++)
      af[mt]  = *(const bf16x8*)(Qs + (wm + mt*16 + l16)*72 + ks*32 + q*8);
    #pragma unroll
    for (int nt = 0; nt < 5; nt++)
      bfr[nt] = *(const bf16x8*)(Bs + (nt*16 + l16)*72 + ks*32 + q*8);
    #pragma unroll
    for (int mt = 0; mt < 2; mt++)
      #pragma unroll
      for (int nt = 0; nt < 5; nt++)
        acc[mt][nt] = __builtin_amdgcn_mfma_f32_16x16x32_bf16(af[mt], bfr[nt], acc[mt][nt], 0, 0, 0);
  }

  #pragma unroll
  for (int mt = 0; mt < 2; mt++){
    #pragma unroll
    for (int r = 0; r < 4; r++){
      float d0 = __shfl(acc[mt][4][r], lane & 48);   // col 64 lives at l16==0
      float z  = 1.f / (d0 + 1e-6f);
      int row  = bm + wm + mt*16 + q*4 + r;
      size_t obase = ((size_t)b*T_ + row)*D_ + h*HD_;
      #pragma unroll
      for (int nt = 0; nt < 4; nt++)
        yb[obase + nt*16 + l16] = f2bf(acc[mt][nt][r] * z);
    }
  }
}

// ---------------------------------------------------------------------------
// Fused: x += cb[b];  xn = LN(x)  (bf16). One wave per row.
// ---------------------------------------------------------------------------
__global__ __launch_bounds__(256)
void ln_add_k(float* __restrict__ x, const float* __restrict__ cb,
              const float* __restrict__ w, const float* __restrict__ b,
              ushort* __restrict__ out)
{
  int wave = threadIdx.x >> 6, lane = threadIdx.x & 63;
  int row  = blockIdx.x*4 + wave;
  int bidx = row / T_;
  float* xr = x + (size_t)row*D_;
  const float* cbr = cb + (size_t)bidx*D_;
  float vals[12], s = 0.f, s2 = 0.f;
  #pragma unroll
  for (int j = 0; j < 12; j++){
    int e = j*64 + lane;
    float v = xr[e] + cbr[e];
    xr[e] = v;
    vals[j] = v; s += v; s2 += v*v;
  }
  #pragma unroll
  for (int o = 32; o > 0; o >>= 1){ s += __shfl_xor(s, o); s2 += __shfl_xor(s2, o); }
  float m   = s  * (1.f/768.f);
  float var = s2 * (1.f/768.f) - m*m;
  float rs  = rsqrtf(var + 1e-5f);
  ushort* orow = out + (size_t)row*D_;
  #pragma unroll
  for (int j = 0; j < 12; j++){
    int e = j*64 + lane;
    orow[e] = f2bf((vals[j] - m)*rs*w[e] + b[e]);
  }
}

// ---------------------------------------------------------------------------
template<int TAIL>
__global__ __launch_bounds__(256)
void ln_k(const float* __restrict__ x, const float* __restrict__ w,
          const float* __restrict__ b, ushort* __restrict__ out)
{
  int wave = threadIdx.x >> 6, lane = threadIdx.x & 63;
  int row  = blockIdx.x*4 + wave;
  size_t prow;
  if (TAIL){ int bb = row >> 10, t = row & 1023; prow = (size_t)bb*T_ + CL_ + t; }
  else     { prow = row; }
  const float* xr = x + prow*D_;
  float vals[12], s = 0.f, s2 = 0.f;
  #pragma unroll
  for (int j = 0; j < 12; j++){
    float v = xr[j*64 + lane]; vals[j] = v; s += v; s2 += v*v;
  }
  #pragma unroll
  for (int o = 32; o > 0; o >>= 1){ s += __shfl_xor(s, o); s2 += __shfl_xor(s2, o); }
  float m  = s  * (1.f/768.f);
  float var = s2 * (1.f/768.f) - m*m;
  float rs = rsqrtf(var + 1e-5f);
  ushort* orow = out + (size_t)row*D_;
  #pragma unroll
  for (int j = 0; j < 12; j++){
    int e = j*64 + lane;
    orow[e] = f2bf((vals[j] - m)*rs*w[e] + b[e]);
  }
}

// ---------------------------------------------------------------------------
// kvm[b,h] = sum_t k^T v (64x64), ksum = sum_t k. Split-K atomics.
// ---------------------------------------------------------------------------
__global__ __launch_bounds__(256)
void kvm_k(const ushort* __restrict__ kb, const ushort* __restrict__ vb,
           float* __restrict__ kvm, float* __restrict__ ksum)
{
  __shared__ ushort Ks[32*64], Vs[32*64];
  int bh = blockIdx.x, slice = blockIdx.y;
  int b  = bh / H_, h = bh - b*H_;
  int tid = threadIdx.x;
  int e = tid & 63, dbase = (tid >> 6) * 16;
  float acc[16];
  #pragma unroll
  for (int i = 0; i < 16; i++) acc[i] = 0.f;
  float ksacc = 0.f;
  int r = tid >> 3, c = (tid & 7) * 8;
  const size_t base = (size_t)b*T_*D_ + h*HD_;
  for (int t0 = slice*384; t0 < slice*384 + 384; t0 += 32){
    *(bf16x8*)(Ks + r*64 + c) = *(const bf16x8*)(kb + base + (size_t)(t0 + r)*D_ + c);
    *(bf16x8*)(Vs + r*64 + c) = *(const bf16x8*)(vb + base + (size_t)(t0 + r)*D_ + c);
    __syncthreads();
    #pragma unroll 8
    for (int j = 0; j < 32; j++){
      float vv = bf2f(Vs[j*64 + e]);
      #pragma unroll
      for (int d = 0; d < 16; d++) acc[d] += bf2f(Ks[j*64 + dbase + d]) * vv;
    }
    if (tid < 64){
      #pragma unroll 8
      for (int j = 0; j < 32; j++) ksacc += bf2f(Ks[j*64 + tid]);
    }
    __syncthreads();
  }
  float* kv = kvm + (size_t)bh*4096;
  #pragma unroll
  for (int d = 0; d < 16; d++) atomicAdd(&kv[(dbase + d)*64 + e], acc[d]);
  if (tid < 64) atomicAdd(&ksum[bh*64 + tid], ksacc);
}

// ---------------------------------------------------------------------------
__global__ __launch_bounds__(256)
void build_x_k(const float* __restrict__ ctx, const float* __restrict__ mq,
               const int* __restrict__ tgt, float* __restrict__ x)
{
  int idx = blockIdx.x*256 + threadIdx.x;   // float4 index
  int c  = idx % 192;
  int bt = idx / 192;
  int t  = bt % T_, b = bt / T_;
  float4 v;
  if (t < CL_) v = ((const float4*)ctx)[((size_t)b*CL_ + t)*192 + c];
  else {
    int g = tgt[b*TT_ + (t - CL_)];
    v = ((const float4*)mq)[(size_t)g*192 + c];
  }
  ((float4*)x)[idx] = v;
}

// ---------------------------------------------------------------------------
__global__ __launch_bounds__(256)
void act1_k(const float* __restrict__ act, const float* __restrict__ w1,
            const float* __restrict__ b1, const float* __restrict__ lnw,
            const float* __restrict__ lnb, float* __restrict__ a1)
{
  __shared__ float buf[768];
  __shared__ float red[256];
  int b = blockIdx.x, tid = threadIdx.x;
  const float* ar = act + b*AD_;
  for (int j = tid; j < 768; j += 256){
    float s = b1[j];
    for (int k = 0; k < AD_; k++) s += ar[k]*w1[k*768 + j];
    buf[j] = s;
  }
  __syncthreads();
  red[tid] = buf[tid] + buf[tid+256] + buf[tid+512];
  __syncthreads();
  for (int o = 128; o > 0; o >>= 1){ if (tid < o) red[tid] += red[tid+o]; __syncthreads(); }
  float m = red[0]*(1.f/768.f);
  __syncthreads();
  float v0 = buf[tid]-m, v1 = buf[tid+256]-m, v2 = buf[tid+512]-m;
  red[tid] = v0*v0 + v1*v1 + v2*v2;
  __syncthreads();
  for (int o = 128; o > 0; o >>= 1){ if (tid < o) red[tid] += red[tid+o]; __syncthreads(); }
  float rs = rsqrtf(red[0]*(1.f/768.f) + 1e-5f);
  __syncthreads();
  for (int j = tid; j < 768; j += 256){
    float v = (buf[j]-m)*rs*lnw[j] + lnb[j];
    a1[b*768 + j] = 0.5f*v*(1.f + erff(v*0.70710678118654752f));
  }
}

__global__ __launch_bounds__(256)
void act2_k(const float* __restrict__ a1, const float* __restrict__ w2,
            const float* __restrict__ b2, float* __restrict__ emb)
{
  __shared__ float inb[768];
  int b = blockIdx.x, tid = threadIdx.x;
  for (int j = tid; j < 768; j += 256) inb[j] = a1[b*768 + j];
  __syncthreads();
  for (int j = tid; j < 768; j += 256){
    float s = b2[j];
    for (int k = 0; k < 768; k++) s += inb[k]*w2[k*768 + j];
    emb[b*768 + j] = s;
  }
}

// ---------------------------------------------------------------------------
// Collapsed cross-attn bias path, parallel split-K version.
// cinit: tmp[l,b,:] = a_vb[l]; cb[l,b,:] = a_cb[l]
// cmm<0>: tmp += emb @ a_vw ; cmm<1>: cb += tmp @ a_cw
// ---------------------------------------------------------------------------
__global__ __launch_bounds__(256)
void cinit_k(const float* __restrict__ vb, const float* __restrict__ cbv,
             float* __restrict__ tmp, float* __restrict__ cb)
{
  int idx = blockIdx.x*256 + threadIdx.x;     // < 48*768
  int j = idx % 768, l = (idx / 768) / B_;
  tmp[idx] = vb[l*768 + j];
  cb[idx]  = cbv[l*768 + j];
}

template<int IN>
__global__ __launch_bounds__(256)
void cmm_k(const float* __restrict__ inp, const float* __restrict__ W,
           float* __restrict__ out)
{
  __shared__ float ein[8*96];
  int jc = blockIdx.x, kc = blockIdx.y, l = blockIdx.z;
  int tid = threadIdx.x;
  int c = tid & 63, ts = tid >> 6;
  for (int i = tid; i < 768; i += 256){
    int b = i / 96, kk = i - b*96;
    ein[i] = IN ? inp[((size_t)l*B_ + b)*768 + kc*96 + kk]
                : inp[(size_t)b*768 + kc*96 + kk];
  }
  __syncthreads();
  int j = jc*64 + c;
  const float* w = W + (size_t)l*768*768 + j;
  float acc[8] = {0,0,0,0,0,0,0,0};
  for (int kk = ts*24; kk < ts*24 + 24; kk++){
    float wv = w[(size_t)(kc*96 + kk)*768];
    #pragma unroll
    for (int b = 0; b < 8; b++) acc[b] += ein[b*96 + kk] * wv;
  }
  #pragma unroll
  for (int b = 0; b < 8; b++)
    atomicAdd(&out[((size_t)l*B_ + b)*768 + j], acc[b]);
}

// ---------------------------------------------------------------------------
extern "C" void kernel_launch(void* const* d_in, const int* in_sizes, int n_in,
                              void* d_out, int out_size, void* d_ws, size_t ws_size,
                              hipStream_t stream)
{
  (void)in_sizes; (void)n_in; (void)out_size;
  const float* ctx    = (const float*)d_in[0];
  const float* act    = (const float*)d_in[1];
  const int*   tgt    = (const int*)  d_in[2];
  const float* ad_w1  = (const float*)d_in[3];
  const float* ad_b1  = (const float*)d_in[4];
  const float* ad_lnw = (const float*)d_in[5];
  const float* ad_lnb = (const float*)d_in[6];
  const float* ad_w2  = (const float*)d_in[7];
  const float* ad_b2  = (const float*)d_in[8];
  const float* mq     = (const float*)d_in[9];
  // ln1 (10,11), a_qw/qb/kw/kb (12..15) dead: cross-attn collapses to v@cw+cb
  const float* a_vw   = (const float*)d_in[16];
  const float* a_vb   = (const float*)d_in[17];
  const float* a_cw   = (const float*)d_in[18];
  const float* a_cb   = (const float*)d_in[19];
  const float* ln2_w  = (const float*)d_in[20];
  const float* ln2_b  = (const float*)d_in[21];
  const float* s_qw   = (const float*)d_in[22];
  const float* s_qb   = (const float*)d_in[23];
  const float* s_kw   = (const float*)d_in[24];
  const float* s_kb   = (const float*)d_in[25];
  const float* s_vw   = (const float*)d_in[26];
  const float* s_vb   = (const float*)d_in[27];
  const float* s_cw   = (const float*)d_in[28];
  const float* s_cb   = (const float*)d_in[29];
  const float* ln3_w  = (const float*)d_in[30];
  const float* ln3_b  = (const float*)d_in[31];
  const float* mlp_w1 = (const float*)d_in[32];
  const float* mlp_b1 = (const float*)d_in[33];
  const float* mlp_w2 = (const float*)d_in[34];
  const float* mlp_b2 = (const float*)d_in[35];
  const float* fn_w   = (const float*)d_in[36];
  const float* fn_b   = (const float*)d_in[37];
  const float* mu_w   = (const float*)d_in[38];
  const float* mu_b   = (const float*)d_in[39];
  const float* lv_w   = (const float*)d_in[40];
  const float* lv_b   = (const float*)d_in[41];

  char* ws = (char*)d_ws;
  size_t off = 0;
  auto alloc = [&](size_t bytes) -> char* {
    char* p = ws + off; off += (bytes + 255) & ~(size_t)255; return p;
  };
  const size_t NTOK = (size_t)BT_;            // 24576
  float*  x    = (float*) alloc(NTOK*D_*4);          // 75.5 MB residual
  ushort* xn   = (ushort*)alloc(NTOK*D_*2);          // 37.7 MB LN out / pred
  char*   un   = alloc(3*NTOK*D_*2);                 // 113 MB: q,k,v; y->q; h alias
  ushort* qb   = (ushort*)un;
  ushort* kb   = qb + NTOK*D_;
  ushort* vb   = kb + NTOK*D_;
  ushort* hb   = (ushort*)un;                        // (12288,3072) bf16 chunk
  ushort* wl_sq = (ushort*)alloc((size_t)D_*D_*2);   // contiguous q|k|v|c
  ushort* wl_sk = (ushort*)alloc((size_t)D_*D_*2);
  ushort* wl_sv = (ushort*)alloc((size_t)D_*D_*2);
  ushort* wl_sc = (ushort*)alloc((size_t)D_*D_*2);
  ushort* wl_m1 = (ushort*)alloc((size_t)D_*F_*2);
  ushort* wl_m2 = (ushort*)alloc((size_t)F_*D_*2);
  ushort* wt_mu = (ushort*)alloc((size_t)D_*D_*2);   // contiguous mu|lv
  ushort* wt_lv = (ushort*)alloc((size_t)D_*D_*2);
  float*  kvm   = (float*) alloc((size_t)BH_*HD_*HD_*4);
  float*  ksum  = (float*) alloc((size_t)BH_*HD_*4);
  float*  cbias = (float*) alloc((size_t)L_*B_*D_*4);
  float*  ctmp  = (float*) alloc((size_t)L_*B_*D_*4);
  float*  a1    = (float*) alloc((size_t)B_*D_*4);
  float*  emb   = (float*) alloc((size_t)B_*D_*4);

  if (off > ws_size) return;

  dim3 blk(256);

  // heads weights (once)
  tconv_k<<<dim3(12,12), blk, 0, stream>>>(mu_w, wt_mu, D_, D_);
  tconv_k<<<dim3(12,12), blk, 0, stream>>>(lv_w, wt_lv, D_, D_);

  // action path + collapsed cross-attn biases (parallel split-K)
  act1_k<<<B_, blk, 0, stream>>>(act, ad_w1, ad_b1, ad_lnw, ad_lnb, a1);
  act2_k<<<B_, blk, 0, stream>>>(a1, ad_w2, ad_b2, emb);
  cinit_k<<<(L_*B_*D_)/256, blk, 0, stream>>>(a_vb, a_cb, ctmp, cbias);
  cmm_k<0><<<dim3(12,8,L_), blk, 0, stream>>>(emb,  a_vw, ctmp);
  cmm_k<1><<<dim3(12,8,L_), blk, 0, stream>>>(ctmp, a_cw, cbias);

  build_x_k<<<(BT_*192)/256, blk, 0, stream>>>(ctx, mq, tgt, x);

  const int GY = BT_/128;   // 192
  const int NZ4 = (BH_*HD_*HD_ + BH_*HD_) / 4;
  for (int i = 0; i < L_; i++){
    tconv4_k<<<dim3(12,12,4), blk, 0, stream>>>(
        s_qw + (size_t)i*D_*D_, s_kw + (size_t)i*D_*D_,
        s_vw + (size_t)i*D_*D_, s_cw + (size_t)i*D_*D_, wl_sq);
    tconvM_k<<<dim3(48,12,2), blk, 0, stream>>>(
        mlp_w1 + (size_t)i*D_*F_, wl_m1, mlp_w2 + (size_t)i*F_*D_, wl_m2);

    // fused: x += cbias_i; xn = LN2(x)
    ln_add_k<<<BT_/4, blk, 0, stream>>>(x, cbias + (size_t)i*B_*D_,
                                        ln2_w + i*D_, ln2_b + i*D_, xn);

    // fused q|k|v GEMM, N=2304 (weights contiguous), elu+1 on q,k
    gemm_bf16_k<7><<<dim3(18, GY), blk, 0, stream>>>(
        xn, wl_sq, s_qb + i*D_, s_kb + i*D_, s_vb + i*D_,
        qb, nullptr, 2304, D_, D_, D_);

    zero_k<<<(NZ4 + 255)/256, blk, 0, stream>>>((float4*)kvm, NZ4);
    kvm_k<<<dim3(BH_, 8), blk, 0, stream>>>(kb, vb, kvm, ksum);
    y_mfma_k<<<dim3(BH_, T_/128), blk, 0, stream>>>(qb, kvm, ksum, qb);  // in-place

    gemm_bf16_k<3><<<dim3(6, GY), blk, 0, stream>>>(
        qb, wl_sc, s_cb + i*D_, nullptr, nullptr, nullptr, x, D_, D_, D_, D_);

    ln_k<0><<<BT_/4, blk, 0, stream>>>(x, ln3_w + i*D_, ln3_b + i*D_, xn);
    // MLP split over M (two 12288-row halves); m2 keeps full K=3072
    for (int m = 0; m < 2; m++){
      const size_t ro = (size_t)m*12288;
      gemm_bf16_k<2><<<dim3(24, 96), blk, 0, stream>>>(
          xn + ro*D_, wl_m1, mlp_b1 + (size_t)i*F_, nullptr, nullptr,
          hb, nullptr, F_, D_, D_, D_);
      gemm_bf16_k<3><<<dim3(6, 96), blk, 0, stream>>>(
          hb, wl_m2, mlp_b2 + (size_t)i*D_, nullptr, nullptr,
          nullptr, x + ro*D_, D_, F_, F_, F_);
    }
  }

  ln_k<1><<<(B_*TT_)/4, blk, 0, stream>>>(x, fn_w, fn_b, xn);

  // fused heads: N=1536 = [mu | lv(clipped)]
  gemm_bf16_k<6><<<dim3(12, (B_*TT_)/128), blk, 0, stream>>>(
      xn, wt_mu, mu_b, lv_b, nullptr, nullptr, (float*)d_out, 1536, D_, D_, D_);
}